// Round 1
// baseline (346.606 us; speedup 1.0000x reference)
//
#include <hip/hip_runtime.h>
#include <math.h>

#define MTOT 8192   // B*N
#define HD   512    // hidden dim

typedef __attribute__((ext_vector_type(8))) short bf16x8;
typedef __attribute__((ext_vector_type(4))) float floatx4;

__device__ inline unsigned short f2bf(float f) {
    unsigned int u = __float_as_uint(f);
    unsigned int r = (u + 0x7FFFu + ((u >> 16) & 1u)) >> 16;
    return (unsigned short)r;
}
__device__ inline float bf2f(unsigned short h) {
    return __uint_as_float(((unsigned int)h) << 16);
}

// ---------------- CSR build (grid-parallel, multi-dispatch) ----------------
// NOTE: r6/r9/r10 lessons — single-block LDS builds and cooperative grid.sync
// variants are 10-40x slower than this plain 3-dispatch chain. grid.sync on
// MI355X costs ~35us each regardless of dirty-set size; a dispatch boundary
// is ~5-8us. Do not re-fuse.

__global__ void count_deg(const int* __restrict__ dst, int* __restrict__ deg, int E) {
    int i = blockIdx.x * 256 + threadIdx.x;
    if (i < E) atomicAdd(&deg[dst[i]], 1);
}

__global__ __launch_bounds__(1024) void scan_offsets(const int* __restrict__ deg,
                                                     int* __restrict__ offs,
                                                     int* __restrict__ cursor) {
    __shared__ int part[1024];
    int tid = threadIdx.x;
    int base = tid * 8;
    int v[8]; int s = 0;
    #pragma unroll
    for (int i = 0; i < 8; ++i) { v[i] = deg[base + i]; s += v[i]; }
    part[tid] = s;
    __syncthreads();
    for (int off = 1; off < 1024; off <<= 1) {
        int t = (tid >= off) ? part[tid - off] : 0;
        __syncthreads();
        part[tid] += t;
        __syncthreads();
    }
    int run = (tid == 0) ? 0 : part[tid - 1];
    #pragma unroll
    for (int i = 0; i < 8; ++i) {
        offs[base + i] = run;
        cursor[base + i] = run;
        run += v[i];
    }
    if (tid == 1023) offs[MTOT] = run;
}

__global__ void scatter_edges(const int* __restrict__ src, const int* __restrict__ dst,
                              int* __restrict__ cursor, int* __restrict__ csr_src, int E) {
    int i = blockIdx.x * 256 + threadIdx.x;
    if (i < E) {
        int p = atomicAdd(&cursor[dst[i]], 1);
        csr_src[p] = src[i];
    }
}

// ---------------- combined weight + activation split + deg zero ----------------
// z in [0,6): weight matrix z. z == 6: activation split. z == 7: zero deg.

__global__ __launch_bounds__(256) void prep_convert(
    const float* __restrict__ W0, const float* __restrict__ W1,
    const float* __restrict__ W2, const float* __restrict__ W3,
    const float* __restrict__ W4, const float* __restrict__ W5,
    unsigned short* __restrict__ wtbase,
    const float* __restrict__ X,
    unsigned short* __restrict__ Ahi, unsigned short* __restrict__ Alo,
    int* __restrict__ deg)
{
    int z = blockIdx.z;
    if (z == 7) {
        if (blockIdx.x == 0 && blockIdx.y == 0)
            for (int i = threadIdx.x; i < MTOT; i += 256) deg[i] = 0;
        return;
    }
    if (z == 6) {
        int bid = blockIdx.x * 16 + blockIdx.y;       // 0..255
        int t0 = bid * 256 + threadIdx.x;             // 0..65535
        #pragma unroll
        for (int it = 0; it < 16; ++it) {
            int i = (t0 + it * 65536) * 4;
            float4 vv = *(const float4*)(X + i);
            ushort4 h, l;
            h.x = f2bf(vv.x); l.x = f2bf(vv.x - bf2f(h.x));
            h.y = f2bf(vv.y); l.y = f2bf(vv.y - bf2f(h.y));
            h.z = f2bf(vv.z); l.z = f2bf(vv.z - bf2f(h.z));
            h.w = f2bf(vv.w); l.w = f2bf(vv.w - bf2f(h.w));
            *(ushort4*)(Ahi + i) = h;
            *(ushort4*)(Alo + i) = l;
        }
        return;
    }
    const float* W = (z == 0) ? W0 : (z == 1) ? W1 : (z == 2) ? W2
                   : (z == 3) ? W3 : (z == 4) ? W4 : W5;
    int L = z >> 1, lr = z & 1;
    const size_t SZ = (size_t)HD * HD;
    unsigned short* Whi = wtbase + (L * 4 + lr * 2) * SZ;
    unsigned short* Wlo = Whi + SZ;

    __shared__ float t[32][33];
    int bx = blockIdx.x * 32;  // n base
    int by = blockIdx.y * 32;  // k base
    int tx = threadIdx.x & 31, ty = threadIdx.x >> 5;
    for (int i = ty; i < 32; i += 8)
        t[i][tx] = W[(size_t)(by + i) * HD + bx + tx];
    __syncthreads();
    for (int i = ty; i < 32; i += 8) {
        float vv = t[tx][i];
        unsigned short h = f2bf(vv);
        unsigned short l = f2bf(vv - bf2f(h));
        Whi[(size_t)(bx + i) * HD + by + tx] = h;
        Wlo[(size_t)(bx + i) * HD + by + tx] = l;
    }
}

// ---------------- split-bf16 MFMA dual GEMM (m97 structure) ----------------
// ~31us/dispatch = at the m97-class throughput ceiling for this shape.
// Epilogue additionally emits spart[row][8]: per-64-col partials of
// a . (C_row + bias) so the aggregation kernel gets sl[j]/sr[i] for free
// (score linear-part decomposition; numerically matches the old fp32 a.xl path).

__global__ __launch_bounds__(256) void gemm_mfma_dual(
    const unsigned short* __restrict__ Ahi, const unsigned short* __restrict__ Alo,
    const unsigned short* __restrict__ Bhi_l, const unsigned short* __restrict__ Blo_l,
    const unsigned short* __restrict__ Bhi_r, const unsigned short* __restrict__ Blo_r,
    const float* __restrict__ bias_l, const float* __restrict__ bias_r,
    float* __restrict__ Cl, float* __restrict__ Cr,
    const float* __restrict__ avec,
    float* __restrict__ slpart, float* __restrict__ srpart)
{
    const unsigned short* Bhi = blockIdx.z ? Bhi_r : Bhi_l;
    const unsigned short* Blo = blockIdx.z ? Blo_r : Blo_l;
    const float* bias         = blockIdx.z ? bias_r : bias_l;
    float* C                  = blockIdx.z ? Cr : Cl;
    float* spart              = blockIdx.z ? srpart : slpart;

    __shared__ __align__(16) unsigned short lds[4 * 128 * 32];

    int tid = threadIdx.x;
    int wave = tid >> 6, lane = tid & 63;
    int bm = blockIdx.y * 128, bn = blockIdx.x * 128;

    const unsigned short* gsrc[4] = {Ahi, Alo, Bhi, Blo};
    int rowbase[4] = {bm, bm, bn, bn};

    const unsigned short* gbase =
        gsrc[wave] + (size_t)(rowbase[wave] + (lane >> 2)) * 512 + (lane & 3) * 8;

    floatx4 acc[4][4] = {};

    int wm = wave & 1, wn = wave >> 1;
    int lr = lane & 15, lq = lane >> 4;

    for (int k0 = 0; k0 < 512; k0 += 32) {
        const unsigned short* g = gbase + k0;
        #pragma unroll
        for (int rg = 0; rg < 8; ++rg) {
            __builtin_amdgcn_global_load_lds(
                (const __attribute__((address_space(1))) unsigned int*)(g + (size_t)rg * 16 * 512),
                (__attribute__((address_space(3))) unsigned int*)(&lds[wave * 4096 + rg * 512]),
                16, 0, 0);
        }
        __syncthreads();

        bf16x8 ah[4], al[4], bh[4], bl_[4];
        #pragma unroll
        for (int i = 0; i < 4; ++i) {
            int mrow = wm * 64 + i * 16 + lr;
            ah[i]  = *(const bf16x8*)&lds[0 * 4096 + mrow * 32 + lq * 8];
            al[i]  = *(const bf16x8*)&lds[1 * 4096 + mrow * 32 + lq * 8];
            int nrow = wn * 64 + i * 16 + lr;
            bh[i]  = *(const bf16x8*)&lds[2 * 4096 + nrow * 32 + lq * 8];
            bl_[i] = *(const bf16x8*)&lds[3 * 4096 + nrow * 32 + lq * 8];
        }
        #pragma unroll
        for (int i = 0; i < 4; ++i)
            #pragma unroll
            for (int j = 0; j < 4; ++j) {
                acc[i][j] = __builtin_amdgcn_mfma_f32_16x16x32_bf16(ah[i], bh[j],  acc[i][j], 0, 0, 0);
                acc[i][j] = __builtin_amdgcn_mfma_f32_16x16x32_bf16(ah[i], bl_[j], acc[i][j], 0, 0, 0);
                acc[i][j] = __builtin_amdgcn_mfma_f32_16x16x32_bf16(al[i], bh[j],  acc[i][j], 0, 0, 0);
            }
        __syncthreads();
    }

    #pragma unroll
    for (int j = 0; j < 4; ++j) {
        int n = bn + wn * 64 + j * 16 + lr;
        float bv = bias[n];
        #pragma unroll
        for (int i = 0; i < 4; ++i) {
            int mbase = bm + wm * 64 + i * 16 + lq * 4;
            #pragma unroll
            for (int r = 0; r < 4; ++r)
                C[(size_t)(mbase + r) * 512 + n] = acc[i][j][r] + bv;
        }
    }

    // ---- a-dot partial reduction: spart[row][bx*2+wn] = sum over this
    // wave's 64 cols of a[n]*(C[row,n]) including the bias term. ----
    {
        float aj[4], bj[4];
        #pragma unroll
        for (int j = 0; j < 4; ++j) {
            int n = bn + wn * 64 + j * 16 + lr;
            aj[j] = avec[n];
            bj[j] = bias[n];
        }
        // per-thread bias contribution over its 4 cols (counted once per col
        // across lr/j/wn/bx, so summing partials yields the full a.bias)
        float badd = fmaf(aj[0], bj[0], fmaf(aj[1], bj[1],
                     fmaf(aj[2], bj[2], aj[3] * bj[3])));
        #pragma unroll
        for (int i = 0; i < 4; ++i) {
            #pragma unroll
            for (int r = 0; r < 4; ++r) {
                float v = fmaf(aj[0], acc[i][0][r],
                          fmaf(aj[1], acc[i][1][r],
                          fmaf(aj[2], acc[i][2][r],
                          fmaf(aj[3], acc[i][3][r], badd))));
                v += __shfl_xor(v, 1, 64);
                v += __shfl_xor(v, 2, 64);
                v += __shfl_xor(v, 4, 64);
                v += __shfl_xor(v, 8, 64);
                if (lr == 0) {
                    int row = bm + wm * 64 + i * 16 + lq * 4 + r;
                    spart[(size_t)row * 8 + blockIdx.x * 2 + wn] = v;
                }
            }
        }
    }
}

// ---------------- online-softmax aggregation (flash-style, v4) ----------------
// Replaces the 3-phase LDS kernel: one wave per node, zero LDS, zero barriers.
// Per edge: one coalesced 2KB xl-row read (vs 2 reads in v3), score via
// e = 0.6*(sl[j]+sr[i]) + 0.4*(a.|xl[j]+xr[i]|), online max/sum/acc update
// (wave-uniform branch), 2-deep index / 1-deep data prefetch.
// 2048 blocks x 4 waves fills all 8192 wave slots; gid&7 = graph = XCD so
// each graph's 2MB xl slice stays resident in its XCD's 4MB L2.

__global__ __launch_bounds__(256) void gat_online(
    const float* __restrict__ xl, const float* __restrict__ xr,
    const float* __restrict__ slpart, const float* __restrict__ srpart,
    const float* __restrict__ avec, const float* __restrict__ bias,
    const int* __restrict__ offs, const int* __restrict__ csr_src,
    float* __restrict__ out, unsigned short* __restrict__ Ohi,
    unsigned short* __restrict__ Olo, int write_fp32)
{
    int gid = blockIdx.x;
    int wv = threadIdx.x >> 6, lane = threadIdx.x & 63;
    int node = ((gid & 7) << 10) + ((gid >> 3) << 2) + wv;

    int nb = offs[node], ne = offs[node + 1];

    size_t rowoff = (size_t)node * HD + lane * 8;
    float4 r0 = *(const float4*)(xr + rowoff);
    float4 r1 = *(const float4*)(xr + rowoff + 4);
    float4 av0 = *(const float4*)(avec + lane * 8);
    float4 av1 = *(const float4*)(avec + lane * 8 + 4);

    float4 sr0 = *(const float4*)(srpart + (size_t)node * 8);
    float4 sr1 = *(const float4*)(srpart + (size_t)node * 8 + 4);
    float sr = ((sr0.x + sr0.y) + (sr0.z + sr0.w)) + ((sr1.x + sr1.y) + (sr1.z + sr1.w));

    float m = -3.0e38f, s = 0.f;
    float4 acc0 = {0.f, 0.f, 0.f, 0.f}, acc1 = {0.f, 0.f, 0.f, 0.f};

    int p = nb;
    int jnx = 0;
    float4 nx0 = {0,0,0,0}, nx1 = {0,0,0,0}, nsl0 = {0,0,0,0}, nsl1 = {0,0,0,0};
    if (p < ne) {
        int j0 = __builtin_amdgcn_readfirstlane(csr_src[p]);
        const float* xp = xl + (size_t)j0 * HD + lane * 8;
        nx0 = *(const float4*)xp;
        nx1 = *(const float4*)(xp + 4);
        nsl0 = *(const float4*)(slpart + (size_t)j0 * 8);
        nsl1 = *(const float4*)(slpart + (size_t)j0 * 8 + 4);
    }
    if (p + 1 < ne) jnx = __builtin_amdgcn_readfirstlane(csr_src[p + 1]);

    while (p < ne) {
        float4 cx0 = nx0, cx1 = nx1;
        float slj = ((nsl0.x + nsl0.y) + (nsl0.z + nsl0.w)) +
                    ((nsl1.x + nsl1.y) + (nsl1.z + nsl1.w));

        int jpre = jnx;
        if (p + 2 < ne) jnx = __builtin_amdgcn_readfirstlane(csr_src[p + 2]);
        if (p + 1 < ne) {
            const float* xp = xl + (size_t)jpre * HD + lane * 8;
            nx0 = *(const float4*)xp;
            nx1 = *(const float4*)(xp + 4);
            nsl0 = *(const float4*)(slpart + (size_t)jpre * 8);
            nsl1 = *(const float4*)(slpart + (size_t)jpre * 8 + 4);
        }

        float t, pe = 0.f;
        t = cx0.x + r0.x; pe = fmaf(av0.x, fabsf(t), pe);
        t = cx0.y + r0.y; pe = fmaf(av0.y, fabsf(t), pe);
        t = cx0.z + r0.z; pe = fmaf(av0.z, fabsf(t), pe);
        t = cx0.w + r0.w; pe = fmaf(av0.w, fabsf(t), pe);
        t = cx1.x + r1.x; pe = fmaf(av1.x, fabsf(t), pe);
        t = cx1.y + r1.y; pe = fmaf(av1.y, fabsf(t), pe);
        t = cx1.z + r1.z; pe = fmaf(av1.z, fabsf(t), pe);
        t = cx1.w + r1.w; pe = fmaf(av1.w, fabsf(t), pe);
        pe += __shfl_xor(pe, 1, 64);
        pe += __shfl_xor(pe, 2, 64);
        pe += __shfl_xor(pe, 4, 64);
        pe += __shfl_xor(pe, 8, 64);
        pe += __shfl_xor(pe, 16, 64);
        pe += __shfl_xor(pe, 32, 64);

        float e = fmaf(0.4f, pe, 0.6f * (slj + sr));

        float w;
        if (e > m) {                      // wave-uniform branch (e,m uniform)
            float sc = __expf(m - e);     // first edge: exp(-inf) = 0
            s *= sc;
            acc0.x *= sc; acc0.y *= sc; acc0.z *= sc; acc0.w *= sc;
            acc1.x *= sc; acc1.y *= sc; acc1.z *= sc; acc1.w *= sc;
            m = e; w = 1.f;
        } else {
            w = __expf(e - m);
        }
        s += w;
        acc0.x = fmaf(w, cx0.x, acc0.x);
        acc0.y = fmaf(w, cx0.y, acc0.y);
        acc0.z = fmaf(w, cx0.z, acc0.z);
        acc0.w = fmaf(w, cx0.w, acc0.w);
        acc1.x = fmaf(w, cx1.x, acc1.x);
        acc1.y = fmaf(w, cx1.y, acc1.y);
        acc1.z = fmaf(w, cx1.z, acc1.z);
        acc1.w = fmaf(w, cx1.w, acc1.w);
        ++p;
    }

    float inv = (s > 0.f) ? 1.f / s : 0.f;   // deg==0 -> out = bias (matches ref)
    float4 b0 = *(const float4*)(bias + lane * 8);
    float4 b1 = *(const float4*)(bias + lane * 8 + 4);
    float4 o0, o1;
    o0.x = fmaf(acc0.x, inv, b0.x); o0.y = fmaf(acc0.y, inv, b0.y);
    o0.z = fmaf(acc0.z, inv, b0.z); o0.w = fmaf(acc0.w, inv, b0.w);
    o1.x = fmaf(acc1.x, inv, b1.x); o1.y = fmaf(acc1.y, inv, b1.y);
    o1.z = fmaf(acc1.z, inv, b1.z); o1.w = fmaf(acc1.w, inv, b1.w);

    if (write_fp32) {
        *(float4*)(out + rowoff) = o0;
        *(float4*)(out + rowoff + 4) = o1;
    } else {
        ushort4 h, lo;
        h.x = f2bf(o0.x); lo.x = f2bf(o0.x - bf2f(h.x));
        h.y = f2bf(o0.y); lo.y = f2bf(o0.y - bf2f(h.y));
        h.z = f2bf(o0.z); lo.z = f2bf(o0.z - bf2f(h.z));
        h.w = f2bf(o0.w); lo.w = f2bf(o0.w - bf2f(h.w));
        *(ushort4*)(Ohi + rowoff) = h;
        *(ushort4*)(Olo + rowoff) = lo;
        h.x = f2bf(o1.x); lo.x = f2bf(o1.x - bf2f(h.x));
        h.y = f2bf(o1.y); lo.y = f2bf(o1.y - bf2f(h.y));
        h.z = f2bf(o1.z); lo.z = f2bf(o1.z - bf2f(h.z));
        h.w = f2bf(o1.w); lo.w = f2bf(o1.w - bf2f(h.w));
        *(ushort4*)(Ohi + rowoff + 4) = h;
        *(ushort4*)(Olo + rowoff + 4) = lo;
    }
}

// ---------------- launch ----------------

extern "C" void kernel_launch(void* const* d_in, const int* in_sizes, int n_in,
                              void* d_out, int out_size, void* d_ws, size_t ws_size,
                              hipStream_t stream) {
    const float* x0 = (const float*)d_in[0];
    const int* eidx = (const int*)d_in[2];
    int E = in_sizes[2] / 2;
    const int* esrc = eidx;
    const int* edst = eidx + E;

    const float* Wl[3] = {(const float*)d_in[3],  (const float*)d_in[9],  (const float*)d_in[15]};
    const float* bl[3] = {(const float*)d_in[4],  (const float*)d_in[10], (const float*)d_in[16]};
    const float* Wr[3] = {(const float*)d_in[5],  (const float*)d_in[11], (const float*)d_in[17]};
    const float* br[3] = {(const float*)d_in[6],  (const float*)d_in[12], (const float*)d_in[18]};
    const float* av[3] = {(const float*)d_in[7],  (const float*)d_in[13], (const float*)d_in[19]};
    const float* bs[3] = {(const float*)d_in[8],  (const float*)d_in[14], (const float*)d_in[20]};

    char* w = (char*)d_ws;
    unsigned short* Ahi = (unsigned short*)w; w += (size_t)MTOT * HD * 2;
    unsigned short* Alo = (unsigned short*)w; w += (size_t)MTOT * HD * 2;
    unsigned short* wtbase = (unsigned short*)w; w += 12 * (size_t)HD * HD * 2;
    float* xl = (float*)w; w += (size_t)MTOT * HD * 4;
    float* xr = (float*)w; w += (size_t)MTOT * HD * 4;
    int* deg    = (int*)w;
    int* offs   = deg + MTOT;
    int* cursor = offs + MTOT + 8;
    int* csr    = cursor + MTOT;
    float* slpart = (float*)(((uintptr_t)(csr + E) + 63) & ~(uintptr_t)63);
    float* srpart = slpart + (size_t)MTOT * 8;
    const size_t SZ = (size_t)HD * HD;

    prep_convert<<<dim3(16, 16, 8), 256, 0, stream>>>(
        Wl[0], Wr[0], Wl[1], Wr[1], Wl[2], Wr[2], wtbase, x0, Ahi, Alo, deg);
    count_deg<<<(E + 255) / 256, 256, 0, stream>>>(edst, deg, E);
    scan_offsets<<<1, 1024, 0, stream>>>(deg, offs, cursor);
    scatter_edges<<<(E + 255) / 256, 256, 0, stream>>>(esrc, edst, cursor, csr, E);

    dim3 ggrid(HD / 128, MTOT / 128, 2);
    for (int L = 0; L < 3; ++L) {
        gemm_mfma_dual<<<ggrid, 256, 0, stream>>>(Ahi, Alo,
            wtbase + (L * 4 + 0) * SZ, wtbase + (L * 4 + 1) * SZ,
            wtbase + (L * 4 + 2) * SZ, wtbase + (L * 4 + 3) * SZ,
            bl[L], br[L], xl, xr, av[L], slpart, srpart);
        int last = (L == 2);
        gat_online<<<MTOT / 4, 256, 0, stream>>>(xl, xr, slpart, srpart, av[L], bs[L],
                                                 offs, csr,
                                                 last ? (float*)d_out : nullptr,
                                                 last ? nullptr : Ahi,
                                                 last ? nullptr : Alo,
                                                 last);
    }
}

// Round 2
// 321.331 us; speedup vs baseline: 1.0787x; 1.0787x over previous
//
#include <hip/hip_runtime.h>
#include <math.h>

#define MTOT 8192   // B*N
#define HD   512    // hidden dim

typedef __attribute__((ext_vector_type(8))) short bf16x8;
typedef __attribute__((ext_vector_type(4))) float floatx4;

__device__ inline unsigned short f2bf(float f) {
    unsigned int u = __float_as_uint(f);
    unsigned int r = (u + 0x7FFFu + ((u >> 16) & 1u)) >> 16;
    return (unsigned short)r;
}
__device__ inline float bf2f(unsigned short h) {
    return __uint_as_float(((unsigned int)h) << 16);
}

// ---------------- CSR build (grid-parallel, multi-dispatch) ----------------
// NOTE: r6/r9/r10 lessons — single-block LDS builds and cooperative grid.sync
// variants are 10-40x slower than this plain 3-dispatch chain. grid.sync on
// MI355X costs ~35us each regardless of dirty-set size; a dispatch boundary
// is ~5-8us. Do not re-fuse.

__global__ void count_deg(const int* __restrict__ dst, int* __restrict__ deg, int E) {
    int i = blockIdx.x * 256 + threadIdx.x;
    if (i < E) atomicAdd(&deg[dst[i]], 1);
}

__global__ __launch_bounds__(1024) void scan_offsets(const int* __restrict__ deg,
                                                     int* __restrict__ offs,
                                                     int* __restrict__ cursor) {
    __shared__ int part[1024];
    int tid = threadIdx.x;
    int base = tid * 8;
    int v[8]; int s = 0;
    #pragma unroll
    for (int i = 0; i < 8; ++i) { v[i] = deg[base + i]; s += v[i]; }
    part[tid] = s;
    __syncthreads();
    for (int off = 1; off < 1024; off <<= 1) {
        int t = (tid >= off) ? part[tid - off] : 0;
        __syncthreads();
        part[tid] += t;
        __syncthreads();
    }
    int run = (tid == 0) ? 0 : part[tid - 1];
    #pragma unroll
    for (int i = 0; i < 8; ++i) {
        offs[base + i] = run;
        cursor[base + i] = run;
        run += v[i];
    }
    if (tid == 1023) offs[MTOT] = run;
}

__global__ void scatter_edges(const int* __restrict__ src, const int* __restrict__ dst,
                              int* __restrict__ cursor, int* __restrict__ csr_src, int E) {
    int i = blockIdx.x * 256 + threadIdx.x;
    if (i < E) {
        int p = atomicAdd(&cursor[dst[i]], 1);
        csr_src[p] = src[i];
    }
}

// ---------------- combined weight + activation split + deg zero ----------------
// z in [0,6): weight matrix z. z == 6: activation split. z == 7: zero deg.

__global__ __launch_bounds__(256) void prep_convert(
    const float* __restrict__ W0, const float* __restrict__ W1,
    const float* __restrict__ W2, const float* __restrict__ W3,
    const float* __restrict__ W4, const float* __restrict__ W5,
    unsigned short* __restrict__ wtbase,
    const float* __restrict__ X,
    unsigned short* __restrict__ Ahi, unsigned short* __restrict__ Alo,
    int* __restrict__ deg)
{
    int z = blockIdx.z;
    if (z == 7) {
        if (blockIdx.x == 0 && blockIdx.y == 0)
            for (int i = threadIdx.x; i < MTOT; i += 256) deg[i] = 0;
        return;
    }
    if (z == 6) {
        int bid = blockIdx.x * 16 + blockIdx.y;       // 0..255
        int t0 = bid * 256 + threadIdx.x;             // 0..65535
        #pragma unroll
        for (int it = 0; it < 16; ++it) {
            int i = (t0 + it * 65536) * 4;
            float4 vv = *(const float4*)(X + i);
            ushort4 h, l;
            h.x = f2bf(vv.x); l.x = f2bf(vv.x - bf2f(h.x));
            h.y = f2bf(vv.y); l.y = f2bf(vv.y - bf2f(h.y));
            h.z = f2bf(vv.z); l.z = f2bf(vv.z - bf2f(h.z));
            h.w = f2bf(vv.w); l.w = f2bf(vv.w - bf2f(h.w));
            *(ushort4*)(Ahi + i) = h;
            *(ushort4*)(Alo + i) = l;
        }
        return;
    }
    const float* W = (z == 0) ? W0 : (z == 1) ? W1 : (z == 2) ? W2
                   : (z == 3) ? W3 : (z == 4) ? W4 : W5;
    int L = z >> 1, lr = z & 1;
    const size_t SZ = (size_t)HD * HD;
    unsigned short* Whi = wtbase + (L * 4 + lr * 2) * SZ;
    unsigned short* Wlo = Whi + SZ;

    __shared__ float t[32][33];
    int bx = blockIdx.x * 32;  // n base
    int by = blockIdx.y * 32;  // k base
    int tx = threadIdx.x & 31, ty = threadIdx.x >> 5;
    for (int i = ty; i < 32; i += 8)
        t[i][tx] = W[(size_t)(by + i) * HD + bx + tx];
    __syncthreads();
    for (int i = ty; i < 32; i += 8) {
        float vv = t[tx][i];
        unsigned short h = f2bf(vv);
        unsigned short l = f2bf(vv - bf2f(h));
        Whi[(size_t)(bx + i) * HD + by + tx] = h;
        Wlo[(size_t)(bx + i) * HD + by + tx] = l;
    }
}

// ---------------- split-bf16 MFMA dual GEMM (m97 structure) ----------------
// ~31us/dispatch = at the m97-class throughput ceiling for this shape.
// (round-0 form; the a-dot epilogue experiment was reverted — the score's
// linear term is now folded into the agg kernel's per-element lrelu math)

__global__ __launch_bounds__(256) void gemm_mfma_dual(
    const unsigned short* __restrict__ Ahi, const unsigned short* __restrict__ Alo,
    const unsigned short* __restrict__ Bhi_l, const unsigned short* __restrict__ Blo_l,
    const unsigned short* __restrict__ Bhi_r, const unsigned short* __restrict__ Blo_r,
    const float* __restrict__ bias_l, const float* __restrict__ bias_r,
    float* __restrict__ Cl, float* __restrict__ Cr)
{
    const unsigned short* Bhi = blockIdx.z ? Bhi_r : Bhi_l;
    const unsigned short* Blo = blockIdx.z ? Blo_r : Blo_l;
    const float* bias         = blockIdx.z ? bias_r : bias_l;
    float* C                  = blockIdx.z ? Cr : Cl;

    __shared__ __align__(16) unsigned short lds[4 * 128 * 32];

    int tid = threadIdx.x;
    int wave = tid >> 6, lane = tid & 63;
    int bm = blockIdx.y * 128, bn = blockIdx.x * 128;

    const unsigned short* gsrc[4] = {Ahi, Alo, Bhi, Blo};
    int rowbase[4] = {bm, bm, bn, bn};

    const unsigned short* gbase =
        gsrc[wave] + (size_t)(rowbase[wave] + (lane >> 2)) * 512 + (lane & 3) * 8;

    floatx4 acc[4][4] = {};

    int wm = wave & 1, wn = wave >> 1;
    int lr = lane & 15, lq = lane >> 4;

    for (int k0 = 0; k0 < 512; k0 += 32) {
        const unsigned short* g = gbase + k0;
        #pragma unroll
        for (int rg = 0; rg < 8; ++rg) {
            __builtin_amdgcn_global_load_lds(
                (const __attribute__((address_space(1))) unsigned int*)(g + (size_t)rg * 16 * 512),
                (__attribute__((address_space(3))) unsigned int*)(&lds[wave * 4096 + rg * 512]),
                16, 0, 0);
        }
        __syncthreads();

        bf16x8 ah[4], al[4], bh[4], bl_[4];
        #pragma unroll
        for (int i = 0; i < 4; ++i) {
            int mrow = wm * 64 + i * 16 + lr;
            ah[i]  = *(const bf16x8*)&lds[0 * 4096 + mrow * 32 + lq * 8];
            al[i]  = *(const bf16x8*)&lds[1 * 4096 + mrow * 32 + lq * 8];
            int nrow = wn * 64 + i * 16 + lr;
            bh[i]  = *(const bf16x8*)&lds[2 * 4096 + nrow * 32 + lq * 8];
            bl_[i] = *(const bf16x8*)&lds[3 * 4096 + nrow * 32 + lq * 8];
        }
        #pragma unroll
        for (int i = 0; i < 4; ++i)
            #pragma unroll
            for (int j = 0; j < 4; ++j) {
                acc[i][j] = __builtin_amdgcn_mfma_f32_16x16x32_bf16(ah[i], bh[j],  acc[i][j], 0, 0, 0);
                acc[i][j] = __builtin_amdgcn_mfma_f32_16x16x32_bf16(ah[i], bl_[j], acc[i][j], 0, 0, 0);
                acc[i][j] = __builtin_amdgcn_mfma_f32_16x16x32_bf16(al[i], bh[j],  acc[i][j], 0, 0, 0);
            }
        __syncthreads();
    }

    #pragma unroll
    for (int j = 0; j < 4; ++j) {
        int n = bn + wn * 64 + j * 16 + lr;
        float bv = bias[n];
        #pragma unroll
        for (int i = 0; i < 4; ++i) {
            int mbase = bm + wm * 64 + i * 16 + lq * 4;
            #pragma unroll
            for (int r = 0; r < 4; ++r)
                C[(size_t)(mbase + r) * 512 + n] = acc[i][j][r] + bv;
        }
    }
}

// ---------------- online-softmax aggregation v5: 4-edge-batched ILP ----------------
// r1 post-mortem: 1-edge-per-iteration online loop was latency-bound (6 dependent
// ds_bpermute per edge + 1-deep prefetch) and tied the old 3-phase kernel (~43us).
// v5 processes 4 edges per batch: 8 dwordx4 row loads in flight, 4 independent
// 6-shfl reduce chains, ONE rescale per batch (batch-max), indices prefetched one
// batch ahead. Score fully per-element: e = sum_d a_d*(0.6*t + 0.4*|t|), t=xl[j]+xr[i]
// — no slpart/srpart coupling. One wave per node, zero LDS, zero barriers.

#define EDGE_DOT8(pe, xa, xb)                                                  \
    {                                                                          \
        float t_, l_;                                                          \
        t_ = xa.x + r0.x; l_ = fmaf(0.4f, fabsf(t_), 0.6f * t_); pe = fmaf(av0.x, l_, pe); \
        t_ = xa.y + r0.y; l_ = fmaf(0.4f, fabsf(t_), 0.6f * t_); pe = fmaf(av0.y, l_, pe); \
        t_ = xa.z + r0.z; l_ = fmaf(0.4f, fabsf(t_), 0.6f * t_); pe = fmaf(av0.z, l_, pe); \
        t_ = xa.w + r0.w; l_ = fmaf(0.4f, fabsf(t_), 0.6f * t_); pe = fmaf(av0.w, l_, pe); \
        t_ = xb.x + r1.x; l_ = fmaf(0.4f, fabsf(t_), 0.6f * t_); pe = fmaf(av1.x, l_, pe); \
        t_ = xb.y + r1.y; l_ = fmaf(0.4f, fabsf(t_), 0.6f * t_); pe = fmaf(av1.y, l_, pe); \
        t_ = xb.z + r1.z; l_ = fmaf(0.4f, fabsf(t_), 0.6f * t_); pe = fmaf(av1.z, l_, pe); \
        t_ = xb.w + r1.w; l_ = fmaf(0.4f, fabsf(t_), 0.6f * t_); pe = fmaf(av1.w, l_, pe); \
    }

__global__ __launch_bounds__(256) void gat_online(
    const float* __restrict__ xl, const float* __restrict__ xr,
    const float* __restrict__ avec, const float* __restrict__ bias,
    const int* __restrict__ offs, const int* __restrict__ csr_src,
    float* __restrict__ out, unsigned short* __restrict__ Ohi,
    unsigned short* __restrict__ Olo, int write_fp32)
{
    int gid = blockIdx.x;
    int wv = threadIdx.x >> 6, lane = threadIdx.x & 63;
    int node = ((gid & 7) << 10) + ((gid >> 3) << 2) + wv;

    int nb = offs[node], ne = offs[node + 1];

    size_t rowoff = (size_t)node * HD + lane * 8;
    float4 r0 = *(const float4*)(xr + rowoff);
    float4 r1 = *(const float4*)(xr + rowoff + 4);
    float4 av0 = *(const float4*)(avec + lane * 8);
    float4 av1 = *(const float4*)(avec + lane * 8 + 4);

    float m = -3.0e38f, s = 0.f;
    float4 acc0 = {0.f, 0.f, 0.f, 0.f}, acc1 = {0.f, 0.f, 0.f, 0.f};

    int p = nb;
    int jc0 = 0, jc1 = 0, jc2 = 0, jc3 = 0;
    if (p < ne) {
        jc0 = csr_src[p];
        jc1 = (p + 1 < ne) ? csr_src[p + 1] : jc0;
        jc2 = (p + 2 < ne) ? csr_src[p + 2] : jc0;
        jc3 = (p + 3 < ne) ? csr_src[p + 3] : jc0;
    }

    while (p < ne) {
        // issue 8 row loads (4 edges x 32B/lane) — 4-deep MLP
        const float* xp0 = xl + (size_t)jc0 * HD + lane * 8;
        const float* xp1 = xl + (size_t)jc1 * HD + lane * 8;
        const float* xp2 = xl + (size_t)jc2 * HD + lane * 8;
        const float* xp3 = xl + (size_t)jc3 * HD + lane * 8;
        float4 xa0 = *(const float4*)xp0, xb0 = *(const float4*)(xp0 + 4);
        float4 xa1 = *(const float4*)xp1, xb1 = *(const float4*)(xp1 + 4);
        float4 xa2 = *(const float4*)xp2, xb2 = *(const float4*)(xp2 + 4);
        float4 xa3 = *(const float4*)xp3, xb3 = *(const float4*)(xp3 + 4);

        bool v1 = (p + 1 < ne), v2 = (p + 2 < ne), v3 = (p + 3 < ne);

        // prefetch next-batch indices (keeps the idx->addr chain 1 batch deep)
        int jn0 = jc0, jn1 = jc0, jn2 = jc0, jn3 = jc0;
        int pn = p + 4;
        if (pn < ne) {
            jn0 = csr_src[pn];
            jn1 = (pn + 1 < ne) ? csr_src[pn + 1] : jn0;
            jn2 = (pn + 2 < ne) ? csr_src[pn + 2] : jn0;
            jn3 = (pn + 3 < ne) ? csr_src[pn + 3] : jn0;
        }

        float pe0 = 0.f, pe1 = 0.f, pe2 = 0.f, pe3 = 0.f;
        EDGE_DOT8(pe0, xa0, xb0);
        EDGE_DOT8(pe1, xa1, xb1);
        EDGE_DOT8(pe2, xa2, xb2);
        EDGE_DOT8(pe3, xa3, xb3);

        // 4 independent butterfly reduces — shfl latency amortized 4x
        #pragma unroll
        for (int off = 1; off < 64; off <<= 1) {
            pe0 += __shfl_xor(pe0, off, 64);
            pe1 += __shfl_xor(pe1, off, 64);
            pe2 += __shfl_xor(pe2, off, 64);
            pe3 += __shfl_xor(pe3, off, 64);
        }

        float e0 = pe0;
        float e1 = v1 ? pe1 : -3.0e38f;
        float e2 = v2 ? pe2 : -3.0e38f;
        float e3 = v3 ? pe3 : -3.0e38f;

        float bm = fmaxf(fmaxf(e0, e1), fmaxf(e2, e3));
        if (bm > m) {                        // wave-uniform; once per batch
            float sc = __expf(m - bm);       // first batch: exp(-inf) = 0
            s *= sc;
            acc0.x *= sc; acc0.y *= sc; acc0.z *= sc; acc0.w *= sc;
            acc1.x *= sc; acc1.y *= sc; acc1.z *= sc; acc1.w *= sc;
            m = bm;
        }
        float w0 = __expf(e0 - m);           // invalid edges: exp(-inf) = 0
        float w1 = __expf(e1 - m);
        float w2 = __expf(e2 - m);
        float w3 = __expf(e3 - m);
        s += (w0 + w1) + (w2 + w3);

        acc0.x = fmaf(w0, xa0.x, fmaf(w1, xa1.x, fmaf(w2, xa2.x, fmaf(w3, xa3.x, acc0.x))));
        acc0.y = fmaf(w0, xa0.y, fmaf(w1, xa1.y, fmaf(w2, xa2.y, fmaf(w3, xa3.y, acc0.y))));
        acc0.z = fmaf(w0, xa0.z, fmaf(w1, xa1.z, fmaf(w2, xa2.z, fmaf(w3, xa3.z, acc0.z))));
        acc0.w = fmaf(w0, xa0.w, fmaf(w1, xa1.w, fmaf(w2, xa2.w, fmaf(w3, xa3.w, acc0.w))));
        acc1.x = fmaf(w0, xb0.x, fmaf(w1, xb1.x, fmaf(w2, xb2.x, fmaf(w3, xb3.x, acc1.x))));
        acc1.y = fmaf(w0, xb0.y, fmaf(w1, xb1.y, fmaf(w2, xb2.y, fmaf(w3, xb3.y, acc1.y))));
        acc1.z = fmaf(w0, xb0.z, fmaf(w1, xb1.z, fmaf(w2, xb2.z, fmaf(w3, xb3.z, acc1.z))));
        acc1.w = fmaf(w0, xb0.w, fmaf(w1, xb1.w, fmaf(w2, xb2.w, fmaf(w3, xb3.w, acc1.w))));

        jc0 = jn0; jc1 = jn1; jc2 = jn2; jc3 = jn3;
        p += 4;
    }

    float inv = (s > 0.f) ? 1.f / s : 0.f;   // deg==0 -> out = bias (matches ref)
    float4 b0 = *(const float4*)(bias + lane * 8);
    float4 b1 = *(const float4*)(bias + lane * 8 + 4);
    float4 o0, o1;
    o0.x = fmaf(acc0.x, inv, b0.x); o0.y = fmaf(acc0.y, inv, b0.y);
    o0.z = fmaf(acc0.z, inv, b0.z); o0.w = fmaf(acc0.w, inv, b0.w);
    o1.x = fmaf(acc1.x, inv, b1.x); o1.y = fmaf(acc1.y, inv, b1.y);
    o1.z = fmaf(acc1.z, inv, b1.z); o1.w = fmaf(acc1.w, inv, b1.w);

    if (write_fp32) {
        *(float4*)(out + rowoff) = o0;
        *(float4*)(out + rowoff + 4) = o1;
    } else {
        ushort4 h, lo;
        h.x = f2bf(o0.x); lo.x = f2bf(o0.x - bf2f(h.x));
        h.y = f2bf(o0.y); lo.y = f2bf(o0.y - bf2f(h.y));
        h.z = f2bf(o0.z); lo.z = f2bf(o0.z - bf2f(h.z));
        h.w = f2bf(o0.w); lo.w = f2bf(o0.w - bf2f(h.w));
        *(ushort4*)(Ohi + rowoff) = h;
        *(ushort4*)(Olo + rowoff) = lo;
        h.x = f2bf(o1.x); lo.x = f2bf(o1.x - bf2f(h.x));
        h.y = f2bf(o1.y); lo.y = f2bf(o1.y - bf2f(h.y));
        h.z = f2bf(o1.z); lo.z = f2bf(o1.z - bf2f(h.z));
        h.w = f2bf(o1.w); lo.w = f2bf(o1.w - bf2f(h.w));
        *(ushort4*)(Ohi + rowoff + 4) = h;
        *(ushort4*)(Olo + rowoff + 4) = lo;
    }
}

// ---------------- launch ----------------

extern "C" void kernel_launch(void* const* d_in, const int* in_sizes, int n_in,
                              void* d_out, int out_size, void* d_ws, size_t ws_size,
                              hipStream_t stream) {
    const float* x0 = (const float*)d_in[0];
    const int* eidx = (const int*)d_in[2];
    int E = in_sizes[2] / 2;
    const int* esrc = eidx;
    const int* edst = eidx + E;

    const float* Wl[3] = {(const float*)d_in[3],  (const float*)d_in[9],  (const float*)d_in[15]};
    const float* bl[3] = {(const float*)d_in[4],  (const float*)d_in[10], (const float*)d_in[16]};
    const float* Wr[3] = {(const float*)d_in[5],  (const float*)d_in[11], (const float*)d_in[17]};
    const float* br[3] = {(const float*)d_in[6],  (const float*)d_in[12], (const float*)d_in[18]};
    const float* av[3] = {(const float*)d_in[7],  (const float*)d_in[13], (const float*)d_in[19]};
    const float* bs[3] = {(const float*)d_in[8],  (const float*)d_in[14], (const float*)d_in[20]};

    char* w = (char*)d_ws;
    unsigned short* Ahi = (unsigned short*)w; w += (size_t)MTOT * HD * 2;
    unsigned short* Alo = (unsigned short*)w; w += (size_t)MTOT * HD * 2;
    unsigned short* wtbase = (unsigned short*)w; w += 12 * (size_t)HD * HD * 2;
    float* xl = (float*)w; w += (size_t)MTOT * HD * 4;
    float* xr = (float*)w; w += (size_t)MTOT * HD * 4;
    int* deg    = (int*)w;
    int* offs   = deg + MTOT;
    int* cursor = offs + MTOT + 8;
    int* csr    = cursor + MTOT;
    const size_t SZ = (size_t)HD * HD;

    prep_convert<<<dim3(16, 16, 8), 256, 0, stream>>>(
        Wl[0], Wr[0], Wl[1], Wr[1], Wl[2], Wr[2], wtbase, x0, Ahi, Alo, deg);
    count_deg<<<(E + 255) / 256, 256, 0, stream>>>(edst, deg, E);
    scan_offsets<<<1, 1024, 0, stream>>>(deg, offs, cursor);
    scatter_edges<<<(E + 255) / 256, 256, 0, stream>>>(esrc, edst, cursor, csr, E);

    dim3 ggrid(HD / 128, MTOT / 128, 2);
    for (int L = 0; L < 3; ++L) {
        gemm_mfma_dual<<<ggrid, 256, 0, stream>>>(Ahi, Alo,
            wtbase + (L * 4 + 0) * SZ, wtbase + (L * 4 + 1) * SZ,
            wtbase + (L * 4 + 2) * SZ, wtbase + (L * 4 + 3) * SZ,
            bl[L], br[L], xl, xr);
        int last = (L == 2);
        gat_online<<<MTOT / 4, 256, 0, stream>>>(xl, xr, av[L], bs[L], offs, csr,
                                                 last ? (float*)d_out : nullptr,
                                                 last ? nullptr : Ahi,
                                                 last ? nullptr : Alo,
                                                 last);
    }
}

// Round 3
// 311.840 us; speedup vs baseline: 1.1115x; 1.0304x over previous
//
#include <hip/hip_runtime.h>
#include <math.h>

#define MTOT 8192   // B*N
#define HD   512    // hidden dim

typedef __attribute__((ext_vector_type(8))) short bf16x8;
typedef __attribute__((ext_vector_type(4))) float floatx4;

__device__ inline unsigned short f2bf(float f) {
    unsigned int u = __float_as_uint(f);
    unsigned int r = (u + 0x7FFFu + ((u >> 16) & 1u)) >> 16;
    return (unsigned short)r;
}
__device__ inline float bf2f(unsigned short h) {
    return __uint_as_float(((unsigned int)h) << 16);
}

// wave-wide sum: 4 DPP row_ror adds (VALU pipe, row=16 lanes) + 2 shfl_xor
// (LDS pipe) for the cross-row levels. Replaces 6 dependent ds_bpermute.
__device__ inline float wave_sum64(float v) {
    int t;
    t = __builtin_amdgcn_update_dpp(0, __float_as_int(v), 0x121, 0xF, 0xF, true); v += __int_as_float(t); // row_ror:1
    t = __builtin_amdgcn_update_dpp(0, __float_as_int(v), 0x122, 0xF, 0xF, true); v += __int_as_float(t); // row_ror:2
    t = __builtin_amdgcn_update_dpp(0, __float_as_int(v), 0x124, 0xF, 0xF, true); v += __int_as_float(t); // row_ror:4
    t = __builtin_amdgcn_update_dpp(0, __float_as_int(v), 0x128, 0xF, 0xF, true); v += __int_as_float(t); // row_ror:8
    v += __shfl_xor(v, 16, 64);
    v += __shfl_xor(v, 32, 64);
    return v;
}

// ---------------- CSR build (grid-parallel, multi-dispatch) ----------------
// NOTE: r6/r9/r10 lessons — single-block LDS builds and cooperative grid.sync
// variants are 10-40x slower than this plain 3-dispatch chain. grid.sync on
// MI355X costs ~35us each regardless of dirty-set size; a dispatch boundary
// is ~5-8us. Do not re-fuse.

__global__ void count_deg(const int* __restrict__ dst, int* __restrict__ deg, int E) {
    int i = blockIdx.x * 256 + threadIdx.x;
    if (i < E) atomicAdd(&deg[dst[i]], 1);
}

__global__ __launch_bounds__(1024) void scan_offsets(const int* __restrict__ deg,
                                                     int* __restrict__ offs,
                                                     int* __restrict__ cursor) {
    __shared__ int part[1024];
    int tid = threadIdx.x;
    int base = tid * 8;
    int v[8]; int s = 0;
    #pragma unroll
    for (int i = 0; i < 8; ++i) { v[i] = deg[base + i]; s += v[i]; }
    part[tid] = s;
    __syncthreads();
    for (int off = 1; off < 1024; off <<= 1) {
        int t = (tid >= off) ? part[tid - off] : 0;
        __syncthreads();
        part[tid] += t;
        __syncthreads();
    }
    int run = (tid == 0) ? 0 : part[tid - 1];
    #pragma unroll
    for (int i = 0; i < 8; ++i) {
        offs[base + i] = run;
        cursor[base + i] = run;
        run += v[i];
    }
    if (tid == 1023) offs[MTOT] = run;
}

__global__ void scatter_edges(const int* __restrict__ src, const int* __restrict__ dst,
                              int* __restrict__ cursor, int* __restrict__ csr_src, int E) {
    int i = blockIdx.x * 256 + threadIdx.x;
    if (i < E) {
        int p = atomicAdd(&cursor[dst[i]], 1);
        csr_src[p] = src[i];
    }
}

// ---------------- combined weight + activation split + deg zero ----------------
// z in [0,6): weight matrix z. z == 6: activation split. z == 7: zero deg.

__global__ __launch_bounds__(256) void prep_convert(
    const float* __restrict__ W0, const float* __restrict__ W1,
    const float* __restrict__ W2, const float* __restrict__ W3,
    const float* __restrict__ W4, const float* __restrict__ W5,
    unsigned short* __restrict__ wtbase,
    const float* __restrict__ X,
    unsigned short* __restrict__ Ahi, unsigned short* __restrict__ Alo,
    int* __restrict__ deg)
{
    int z = blockIdx.z;
    if (z == 7) {
        if (blockIdx.x == 0 && blockIdx.y == 0)
            for (int i = threadIdx.x; i < MTOT; i += 256) deg[i] = 0;
        return;
    }
    if (z == 6) {
        int bid = blockIdx.x * 16 + blockIdx.y;       // 0..255
        int t0 = bid * 256 + threadIdx.x;             // 0..65535
        #pragma unroll
        for (int it = 0; it < 16; ++it) {
            int i = (t0 + it * 65536) * 4;
            float4 vv = *(const float4*)(X + i);
            ushort4 h, l;
            h.x = f2bf(vv.x); l.x = f2bf(vv.x - bf2f(h.x));
            h.y = f2bf(vv.y); l.y = f2bf(vv.y - bf2f(h.y));
            h.z = f2bf(vv.z); l.z = f2bf(vv.z - bf2f(h.z));
            h.w = f2bf(vv.w); l.w = f2bf(vv.w - bf2f(h.w));
            *(ushort4*)(Ahi + i) = h;
            *(ushort4*)(Alo + i) = l;
        }
        return;
    }
    const float* W = (z == 0) ? W0 : (z == 1) ? W1 : (z == 2) ? W2
                   : (z == 3) ? W3 : (z == 4) ? W4 : W5;
    int L = z >> 1, lr = z & 1;
    const size_t SZ = (size_t)HD * HD;
    unsigned short* Whi = wtbase + (L * 4 + lr * 2) * SZ;
    unsigned short* Wlo = Whi + SZ;

    __shared__ float t[32][33];
    int bx = blockIdx.x * 32;  // n base
    int by = blockIdx.y * 32;  // k base
    int tx = threadIdx.x & 31, ty = threadIdx.x >> 5;
    for (int i = ty; i < 32; i += 8)
        t[i][tx] = W[(size_t)(by + i) * HD + bx + tx];
    __syncthreads();
    for (int i = ty; i < 32; i += 8) {
        float vv = t[tx][i];
        unsigned short h = f2bf(vv);
        unsigned short l = f2bf(vv - bf2f(h));
        Whi[(size_t)(bx + i) * HD + by + tx] = h;
        Wlo[(size_t)(bx + i) * HD + by + tx] = l;
    }
}

// ---------------- split-bf16 MFMA dual GEMM (m97 structure) ----------------
// ~31us/dispatch = at the m97-class throughput ceiling for this shape.

__global__ __launch_bounds__(256) void gemm_mfma_dual(
    const unsigned short* __restrict__ Ahi, const unsigned short* __restrict__ Alo,
    const unsigned short* __restrict__ Bhi_l, const unsigned short* __restrict__ Blo_l,
    const unsigned short* __restrict__ Bhi_r, const unsigned short* __restrict__ Blo_r,
    const float* __restrict__ bias_l, const float* __restrict__ bias_r,
    float* __restrict__ Cl, float* __restrict__ Cr)
{
    const unsigned short* Bhi = blockIdx.z ? Bhi_r : Bhi_l;
    const unsigned short* Blo = blockIdx.z ? Blo_r : Blo_l;
    const float* bias         = blockIdx.z ? bias_r : bias_l;
    float* C                  = blockIdx.z ? Cr : Cl;

    __shared__ __align__(16) unsigned short lds[4 * 128 * 32];

    int tid = threadIdx.x;
    int wave = tid >> 6, lane = tid & 63;
    int bm = blockIdx.y * 128, bn = blockIdx.x * 128;

    const unsigned short* gsrc[4] = {Ahi, Alo, Bhi, Blo};
    int rowbase[4] = {bm, bm, bn, bn};

    const unsigned short* gbase =
        gsrc[wave] + (size_t)(rowbase[wave] + (lane >> 2)) * 512 + (lane & 3) * 8;

    floatx4 acc[4][4] = {};

    int wm = wave & 1, wn = wave >> 1;
    int lr = lane & 15, lq = lane >> 4;

    for (int k0 = 0; k0 < 512; k0 += 32) {
        const unsigned short* g = gbase + k0;
        #pragma unroll
        for (int rg = 0; rg < 8; ++rg) {
            __builtin_amdgcn_global_load_lds(
                (const __attribute__((address_space(1))) unsigned int*)(g + (size_t)rg * 16 * 512),
                (__attribute__((address_space(3))) unsigned int*)(&lds[wave * 4096 + rg * 512]),
                16, 0, 0);
        }
        __syncthreads();

        bf16x8 ah[4], al[4], bh[4], bl_[4];
        #pragma unroll
        for (int i = 0; i < 4; ++i) {
            int mrow = wm * 64 + i * 16 + lr;
            ah[i]  = *(const bf16x8*)&lds[0 * 4096 + mrow * 32 + lq * 8];
            al[i]  = *(const bf16x8*)&lds[1 * 4096 + mrow * 32 + lq * 8];
            int nrow = wn * 64 + i * 16 + lr;
            bh[i]  = *(const bf16x8*)&lds[2 * 4096 + nrow * 32 + lq * 8];
            bl_[i] = *(const bf16x8*)&lds[3 * 4096 + nrow * 32 + lq * 8];
        }
        #pragma unroll
        for (int i = 0; i < 4; ++i)
            #pragma unroll
            for (int j = 0; j < 4; ++j) {
                acc[i][j] = __builtin_amdgcn_mfma_f32_16x16x32_bf16(ah[i], bh[j],  acc[i][j], 0, 0, 0);
                acc[i][j] = __builtin_amdgcn_mfma_f32_16x16x32_bf16(ah[i], bl_[j], acc[i][j], 0, 0, 0);
                acc[i][j] = __builtin_amdgcn_mfma_f32_16x16x32_bf16(al[i], bh[j],  acc[i][j], 0, 0, 0);
            }
        __syncthreads();
    }

    #pragma unroll
    for (int j = 0; j < 4; ++j) {
        int n = bn + wn * 64 + j * 16 + lr;
        float bv = bias[n];
        #pragma unroll
        for (int i = 0; i < 4; ++i) {
            int mbase = bm + wm * 64 + i * 16 + lq * 4;
            #pragma unroll
            for (int r = 0; r < 4; ++r)
                C[(size_t)(mbase + r) * 512 + n] = acc[i][j][r] + bv;
        }
    }
}

// ---------------- online-softmax aggregation v6: 8-edge batch + DPP reduce ----------------
// r2 post-mortem: v5 (4-edge batch, 6-level shfl butterfly) = ~36us/dispatch,
// still ~7x above the VALU floor -> latency-bound on (a) 6 dependent ds_bpermute
// per reduce chain, (b) only 4 batches of MLP. v6: 8-edge batches (deg~16 -> 2
// iterations, 16 row-loads in flight), reduce via 4 DPP row_ror adds (VALU) +
// 2 shfl_xor (LDS) per chain, first-batch csr indices issued before xr/avec.
// One wave per node, zero LDS, zero barriers.

__global__ __launch_bounds__(256) void gat_online(
    const float* __restrict__ xl, const float* __restrict__ xr,
    const float* __restrict__ avec, const float* __restrict__ bias,
    const int* __restrict__ offs, const int* __restrict__ csr_src,
    float* __restrict__ out, unsigned short* __restrict__ Ohi,
    unsigned short* __restrict__ Olo, int write_fp32)
{
    int gid = blockIdx.x;
    int wv = threadIdx.x >> 6, lane = threadIdx.x & 63;
    int node = ((gid & 7) << 10) + ((gid >> 3) << 2) + wv;

    int nb = offs[node], ne = offs[node + 1];

    // first-batch indices first, so the gather stream starts ASAP
    int jc[8];
    int j0 = (nb < ne) ? csr_src[nb] : 0;
    jc[0] = j0;
    #pragma unroll
    for (int k = 1; k < 8; ++k)
        jc[k] = (nb + k < ne) ? csr_src[nb + k] : j0;

    size_t rowoff = (size_t)node * HD + lane * 8;
    float4 r0 = *(const float4*)(xr + rowoff);
    float4 r1 = *(const float4*)(xr + rowoff + 4);
    float4 av0 = *(const float4*)(avec + lane * 8);
    float4 av1 = *(const float4*)(avec + lane * 8 + 4);

    float m = -3.0e38f, s = 0.f;
    float4 acc0 = {0.f, 0.f, 0.f, 0.f}, acc1 = {0.f, 0.f, 0.f, 0.f};

    int p = nb;
    while (p < ne) {
        // 16 dwordx4 row loads in flight (8 edges x 32B/lane)
        float4 xa[8], xb[8];
        #pragma unroll
        for (int k = 0; k < 8; ++k) {
            const float* xp = xl + (size_t)jc[k] * HD + lane * 8;
            xa[k] = *(const float4*)xp;
            xb[k] = *(const float4*)(xp + 4);
        }

        // prefetch next-batch indices (keeps idx->addr chain 1 batch deep)
        int pn = p + 8;
        int jn[8];
        #pragma unroll
        for (int k = 0; k < 8; ++k)
            jn[k] = (pn + k < ne) ? csr_src[pn + k] : jc[0];

        // per-edge dot: e = sum_d a_d * (0.6*t + 0.4*|t|), t = xl[j]+xr[i]
        float pe[8];
        #pragma unroll
        for (int k = 0; k < 8; ++k) {
            float t, d = 0.f;
            t = xa[k].x + r0.x; d = fmaf(av0.x, fmaf(0.4f, fabsf(t), 0.6f * t), d);
            t = xa[k].y + r0.y; d = fmaf(av0.y, fmaf(0.4f, fabsf(t), 0.6f * t), d);
            t = xa[k].z + r0.z; d = fmaf(av0.z, fmaf(0.4f, fabsf(t), 0.6f * t), d);
            t = xa[k].w + r0.w; d = fmaf(av0.w, fmaf(0.4f, fabsf(t), 0.6f * t), d);
            t = xb[k].x + r1.x; d = fmaf(av1.x, fmaf(0.4f, fabsf(t), 0.6f * t), d);
            t = xb[k].y + r1.y; d = fmaf(av1.y, fmaf(0.4f, fabsf(t), 0.6f * t), d);
            t = xb[k].z + r1.z; d = fmaf(av1.z, fmaf(0.4f, fabsf(t), 0.6f * t), d);
            t = xb[k].w + r1.w; d = fmaf(av1.w, fmaf(0.4f, fabsf(t), 0.6f * t), d);
            pe[k] = d;
        }

        // 8 independent reduces; DPP stages are VALU so chains interleave freely
        #pragma unroll
        for (int k = 0; k < 8; ++k) pe[k] = wave_sum64(pe[k]);

        float e[8];
        #pragma unroll
        for (int k = 0; k < 8; ++k) e[k] = (p + k < ne) ? pe[k] : -3.0e38f;

        float bm8 = e[0];
        #pragma unroll
        for (int k = 1; k < 8; ++k) bm8 = fmaxf(bm8, e[k]);

        if (bm8 > m) {                       // wave-uniform; <=1 rescale per batch
            float sc = __expf(m - bm8);      // first batch: exp(-inf) = 0
            s *= sc;
            acc0.x *= sc; acc0.y *= sc; acc0.z *= sc; acc0.w *= sc;
            acc1.x *= sc; acc1.y *= sc; acc1.z *= sc; acc1.w *= sc;
            m = bm8;
        }

        float w[8]; float ws = 0.f;
        #pragma unroll
        for (int k = 0; k < 8; ++k) { w[k] = __expf(e[k] - m); ws += w[k]; }
        s += ws;

        #pragma unroll
        for (int k = 0; k < 8; ++k) {
            acc0.x = fmaf(w[k], xa[k].x, acc0.x);
            acc0.y = fmaf(w[k], xa[k].y, acc0.y);
            acc0.z = fmaf(w[k], xa[k].z, acc0.z);
            acc0.w = fmaf(w[k], xa[k].w, acc0.w);
            acc1.x = fmaf(w[k], xb[k].x, acc1.x);
            acc1.y = fmaf(w[k], xb[k].y, acc1.y);
            acc1.z = fmaf(w[k], xb[k].z, acc1.z);
            acc1.w = fmaf(w[k], xb[k].w, acc1.w);
        }

        #pragma unroll
        for (int k = 0; k < 8; ++k) jc[k] = jn[k];
        p += 8;
    }

    float inv = (s > 0.f) ? 1.f / s : 0.f;   // deg==0 -> out = bias (matches ref)
    float4 b0 = *(const float4*)(bias + lane * 8);
    float4 b1 = *(const float4*)(bias + lane * 8 + 4);
    float4 o0, o1;
    o0.x = fmaf(acc0.x, inv, b0.x); o0.y = fmaf(acc0.y, inv, b0.y);
    o0.z = fmaf(acc0.z, inv, b0.z); o0.w = fmaf(acc0.w, inv, b0.w);
    o1.x = fmaf(acc1.x, inv, b1.x); o1.y = fmaf(acc1.y, inv, b1.y);
    o1.z = fmaf(acc1.z, inv, b1.z); o1.w = fmaf(acc1.w, inv, b1.w);

    if (write_fp32) {
        *(float4*)(out + rowoff) = o0;
        *(float4*)(out + rowoff + 4) = o1;
    } else {
        ushort4 h, lo;
        h.x = f2bf(o0.x); lo.x = f2bf(o0.x - bf2f(h.x));
        h.y = f2bf(o0.y); lo.y = f2bf(o0.y - bf2f(h.y));
        h.z = f2bf(o0.z); lo.z = f2bf(o0.z - bf2f(h.z));
        h.w = f2bf(o0.w); lo.w = f2bf(o0.w - bf2f(h.w));
        *(ushort4*)(Ohi + rowoff) = h;
        *(ushort4*)(Olo + rowoff) = lo;
        h.x = f2bf(o1.x); lo.x = f2bf(o1.x - bf2f(h.x));
        h.y = f2bf(o1.y); lo.y = f2bf(o1.y - bf2f(h.y));
        h.z = f2bf(o1.z); lo.z = f2bf(o1.z - bf2f(h.z));
        h.w = f2bf(o1.w); lo.w = f2bf(o1.w - bf2f(h.w));
        *(ushort4*)(Ohi + rowoff + 4) = h;
        *(ushort4*)(Olo + rowoff + 4) = lo;
    }
}

// ---------------- launch ----------------

extern "C" void kernel_launch(void* const* d_in, const int* in_sizes, int n_in,
                              void* d_out, int out_size, void* d_ws, size_t ws_size,
                              hipStream_t stream) {
    const float* x0 = (const float*)d_in[0];
    const int* eidx = (const int*)d_in[2];
    int E = in_sizes[2] / 2;
    const int* esrc = eidx;
    const int* edst = eidx + E;

    const float* Wl[3] = {(const float*)d_in[3],  (const float*)d_in[9],  (const float*)d_in[15]};
    const float* bl[3] = {(const float*)d_in[4],  (const float*)d_in[10], (const float*)d_in[16]};
    const float* Wr[3] = {(const float*)d_in[5],  (const float*)d_in[11], (const float*)d_in[17]};
    const float* br[3] = {(const float*)d_in[6],  (const float*)d_in[12], (const float*)d_in[18]};
    const float* av[3] = {(const float*)d_in[7],  (const float*)d_in[13], (const float*)d_in[19]};
    const float* bs[3] = {(const float*)d_in[8],  (const float*)d_in[14], (const float*)d_in[20]};

    char* w = (char*)d_ws;
    unsigned short* Ahi = (unsigned short*)w; w += (size_t)MTOT * HD * 2;
    unsigned short* Alo = (unsigned short*)w; w += (size_t)MTOT * HD * 2;
    unsigned short* wtbase = (unsigned short*)w; w += 12 * (size_t)HD * HD * 2;
    float* xl = (float*)w; w += (size_t)MTOT * HD * 4;
    float* xr = (float*)w; w += (size_t)MTOT * HD * 4;
    int* deg    = (int*)w;
    int* offs   = deg + MTOT;
    int* cursor = offs + MTOT + 8;
    int* csr    = cursor + MTOT;
    const size_t SZ = (size_t)HD * HD;

    prep_convert<<<dim3(16, 16, 8), 256, 0, stream>>>(
        Wl[0], Wr[0], Wl[1], Wr[1], Wl[2], Wr[2], wtbase, x0, Ahi, Alo, deg);
    count_deg<<<(E + 255) / 256, 256, 0, stream>>>(edst, deg, E);
    scan_offsets<<<1, 1024, 0, stream>>>(deg, offs, cursor);
    scatter_edges<<<(E + 255) / 256, 256, 0, stream>>>(esrc, edst, cursor, csr, E);

    dim3 ggrid(HD / 128, MTOT / 128, 2);
    for (int L = 0; L < 3; ++L) {
        gemm_mfma_dual<<<ggrid, 256, 0, stream>>>(Ahi, Alo,
            wtbase + (L * 4 + 0) * SZ, wtbase + (L * 4 + 1) * SZ,
            wtbase + (L * 4 + 2) * SZ, wtbase + (L * 4 + 3) * SZ,
            bl[L], br[L], xl, xr);
        int last = (L == 2);
        gat_online<<<MTOT / 4, 256, 0, stream>>>(xl, xr, av[L], bs[L], offs, csr,
                                                 last ? (float*)d_out : nullptr,
                                                 last ? nullptr : Ahi,
                                                 last ? nullptr : Alo,
                                                 last);
    }
}